// Round 3
// baseline (42.987 us; speedup 1.0000x reference)
//
#include <hip/hip_runtime.h>
#include <stdint.h>

// Problem constants (from reference setup_inputs)
#define BB   32      // batch
#define SS   2048    // sequence length
#define NCH  30      // char alphabet
#define PP   13      // pattern length
#define NN   512     // number of patterns
#define WW   32      // SS / 64 bit-words per row

#define NB_BITS (BB * NCH)                 // 960 blocks: one per (b,c) row
#define NB_DISC ((PP * NN + 255) / 256)    // 26 blocks for discretize

typedef float floatx4 __attribute__((ext_vector_type(4)));  // clang vector: OK for nontemporal builtin

// ---------------------------------------------------------------------------
// Kernel 1 (fused prep):
//  blocks [0, NB_BITS): build per-(b,c) occurrence bitmaps via __ballot.
//    One block = one (b,c) row of 2048 chars -> 32 uint64 words.
//    Each of 4 waves does 8 ballots; loads are 256B/wave coalesced.
//  blocks [NB_BITS, NB_BITS+NB_DISC): discretize patterns.
//    patterns layout [c=30][p=13][1][n=512], col = p*512+n.
//    Output per column: argmax char; 255 = wildcard (col sum <= 0 ->
//    discrete all-zero, no constraint); 254 = dead (tied max ->
//    pattern_sums gains >=2 from this column but conv contributes at most
//    1 -> pattern can never match).
// ---------------------------------------------------------------------------
__global__ void k_prep(const float* __restrict__ input_,
                       const float* __restrict__ patterns,
                       uint64_t* __restrict__ bits,
                       uint8_t* __restrict__ pat_chars) {
    const int bid = blockIdx.x;
    const int t   = threadIdx.x;
    if (bid < NB_BITS) {
        const int wave = t >> 6;
        const int lane = t & 63;
        const float*   row  = input_ + (size_t)bid * SS;
        uint64_t*      brow = bits + (size_t)bid * WW;
#pragma unroll
        for (int i = 0; i < 8; ++i) {
            int w = wave * 8 + i;
            float v = row[w * 64 + lane];
            uint64_t m = __ballot(v > 0.5f);
            if (lane == 0) brow[w] = m;
        }
    } else {
        int col = (bid - NB_BITS) * 256 + t;   // p*NN + n
        if (col < PP * NN) {
            float mx = -1e30f;
            float sum = 0.f;
            int arg = 0;
            for (int c = 0; c < NCH; ++c) {
                float v = patterns[(size_t)c * (PP * NN) + col];
                sum += v;
                if (v > mx) { mx = v; arg = c; }
            }
            int cnt = 0;
            for (int c = 0; c < NCH; ++c) {
                float v = patterns[(size_t)c * (PP * NN) + col];
                cnt += (v == mx) ? 1 : 0;
            }
            uint8_t o;
            if (!(sum > 0.f))  o = 255;       // wildcard column
            else if (cnt > 1)  o = 254;       // dead pattern marker
            else               o = (uint8_t)arg;
            pat_chars[col] = o;
        }
    }
}

// ---------------------------------------------------------------------------
// Kernel 2: bit-parallel match + expand to fp32.
// Block = 256 threads handles one b and 8 consecutive n.
// Phase A: thread t -> (n_local = t>>5, w = t&31): 64 match bits via 13
//          shifted ANDs of the char bitmaps.  Tail s >= 2036 cleared (pad
//          region of conv) unless the pattern has zero constraints.
// Phase B: LDS-staged expansion, coalesced nontemporal float4 stores.
// ---------------------------------------------------------------------------
__global__ void k_match(const uint8_t* __restrict__ pat_chars,
                        const uint64_t* __restrict__ bits,
                        float* __restrict__ out) {
    __shared__ uint64_t masks[8][WW];
    const int b  = blockIdx.x >> 6;    // 64 n-groups of 8 per batch
    const int ng = blockIdx.x & 63;
    const int t  = threadIdx.x;
    const int nl = t >> 5;
    const int w  = t & (WW - 1);
    const int n  = ng * 8 + nl;

    const uint64_t* bb = bits + (size_t)b * NCH * WW;

    uint64_t m = ~0ULL;
    bool has_any = false;   // sums > 0 ?
    bool dead    = false;
#pragma unroll
    for (int p = 0; p < PP; ++p) {
        int c = pat_chars[p * NN + n];
        if (c == 255) continue;        // wildcard column
        has_any = true;
        if (c == 254) { dead = true; continue; }
        uint64_t lo = bb[c * WW + w];
        uint64_t hi = (w < WW - 1) ? bb[c * WW + w + 1] : 0ULL;
        uint64_t word = (p == 0) ? lo : ((lo >> p) | (hi << (64 - p)));
        m &= word;
    }
    if (dead) m = 0ULL;
    // pad region: s in [2036,2048) must be 0 when pattern_sums > 0
    if (w == WW - 1 && has_any) m &= ((1ULL << 52) - 1);

    masks[nl][w] = m;
    __syncthreads();

    // Phase B: write 8 rows x 2048 floats, coalesced nontemporal float4
    size_t base = ((size_t)b * NN + (size_t)ng * 8) * SS;
#pragma unroll
    for (int r = 0; r < 8; ++r) {
        floatx4* rowp = (floatx4*)(out + base + (size_t)r * SS);
#pragma unroll
        for (int j = 0; j < 2; ++j) {
            int i4 = t + j * 256;              // float4 index within row [0,512)
            uint64_t mm = masks[r][i4 >> 4];
            int sh = (i4 & 15) * 4;
            floatx4 v;
            v.x = ((mm >> (sh + 0)) & 1ULL) ? 1.f : 0.f;
            v.y = ((mm >> (sh + 1)) & 1ULL) ? 1.f : 0.f;
            v.z = ((mm >> (sh + 2)) & 1ULL) ? 1.f : 0.f;
            v.w = ((mm >> (sh + 3)) & 1ULL) ? 1.f : 0.f;
            __builtin_nontemporal_store(v, rowp + i4);
        }
    }
}

// ---------------------------------------------------------------------------
extern "C" void kernel_launch(void* const* d_in, const int* in_sizes, int n_in,
                              void* d_out, int out_size, void* d_ws, size_t ws_size,
                              hipStream_t stream) {
    const float* input_   = (const float*)d_in[0];   // [32,30,2048,1]
    const float* patterns = (const float*)d_in[1];   // [30,13,1,512]
    float* out = (float*)d_out;                      // [32,512,2048,1]

    uint8_t*  pat_chars = (uint8_t*)d_ws;                          // 6656 B
    uint64_t* bits      = (uint64_t*)((char*)d_ws + 8192);         // 245760 B

    // K1: fused bits (960 blocks) + discretize (26 blocks)
    k_prep<<<NB_BITS + NB_DISC, 256, 0, stream>>>(input_, patterns, bits, pat_chars);
    // K2: one block per (b, group-of-8 n) -> 32*64 = 2048 blocks
    k_match<<<BB * (NN / 8), 256, 0, stream>>>(pat_chars, bits, out);
}

// Round 4
// 34.943 us; speedup vs baseline: 1.2302x; 1.2302x over previous
//
#include <hip/hip_runtime.h>
#include <stdint.h>

// Problem constants (from reference setup_inputs)
#define BB   32      // batch
#define SS   2048    // sequence length
#define NCH  30      // char alphabet
#define PP   13      // pattern length
#define NN   512     // number of patterns
#define WW   32      // SS / 64 bit-words per row

#define NB_BITS (BB * NCH)                 // 960 blocks: one per (b,c) row
#define NB_DISC ((PP * NN + 255) / 256)    // 26 blocks for discretize

// ---------------------------------------------------------------------------
// Kernel 1 (fused prep):
//  blocks [0, NB_BITS): build per-(b,c) occurrence bitmaps via __ballot.
//    One block = one (b,c) row of 2048 chars -> 32 uint64 words.
//  blocks [NB_BITS, NB_BITS+NB_DISC): discretize patterns.
//    patterns layout [c=30][p=13][1][n=512], col = p*512+n.
//    Per column: argmax char; 255 = wildcard (col sum <= 0); 254 = dead
//    (tied max -> pattern_sums >= conv_max+1 -> never matches).
// ---------------------------------------------------------------------------
__global__ void k_prep(const float* __restrict__ input_,
                       const float* __restrict__ patterns,
                       uint64_t* __restrict__ bits,
                       uint8_t* __restrict__ pat_chars) {
    const int bid = blockIdx.x;
    const int t   = threadIdx.x;
    if (bid < NB_BITS) {
        const int wave = t >> 6;
        const int lane = t & 63;
        const float*   row  = input_ + (size_t)bid * SS;
        uint64_t*      brow = bits + (size_t)bid * WW;
#pragma unroll
        for (int i = 0; i < 8; ++i) {
            int w = wave * 8 + i;
            float v = row[w * 64 + lane];
            uint64_t m = __ballot(v > 0.5f);
            if (lane == 0) brow[w] = m;
        }
    } else {
        int col = (bid - NB_BITS) * 256 + t;   // p*NN + n
        if (col < PP * NN) {
            float mx = -1e30f;
            float sum = 0.f;
            int arg = 0;
            for (int c = 0; c < NCH; ++c) {
                float v = patterns[(size_t)c * (PP * NN) + col];
                sum += v;
                if (v > mx) { mx = v; arg = c; }
            }
            int cnt = 0;
            for (int c = 0; c < NCH; ++c) {
                float v = patterns[(size_t)c * (PP * NN) + col];
                cnt += (v == mx) ? 1 : 0;
            }
            uint8_t o;
            if (!(sum > 0.f))  o = 255;       // wildcard column
            else if (cnt > 1)  o = 254;       // dead pattern marker
            else               o = (uint8_t)arg;
            pat_chars[col] = o;
        }
    }
}

// ---------------------------------------------------------------------------
// Kernel 2: bit-parallel match + expand to fp32.
// Block = 256 threads handles one b and 8 consecutive n.
// Phase A: thread t -> (n_local = t>>5, w = t&31): 64 match bits via 13
//          shifted ANDs of the char bitmaps.  Tail s >= 2036 cleared (pad
//          region of conv) unless the pattern has zero constraints.
// Phase B: LDS-staged expansion, coalesced plain float4 stores.
//          (NT stores measured SLOWER on gfx950 — R3 post-mortem: 43.0 vs
//           39.4 us; normal L2 write path achieves fill-kernel 6.9 TB/s.)
// ---------------------------------------------------------------------------
__global__ void k_match(const uint8_t* __restrict__ pat_chars,
                        const uint64_t* __restrict__ bits,
                        float* __restrict__ out) {
    __shared__ uint64_t masks[8][WW];
    const int b  = blockIdx.x >> 6;    // 64 n-groups of 8 per batch
    const int ng = blockIdx.x & 63;
    const int t  = threadIdx.x;
    const int nl = t >> 5;
    const int w  = t & (WW - 1);
    const int n  = ng * 8 + nl;

    const uint64_t* bb = bits + (size_t)b * NCH * WW;

    uint64_t m = ~0ULL;
    bool has_any = false;   // sums > 0 ?
    bool dead    = false;
#pragma unroll
    for (int p = 0; p < PP; ++p) {
        int c = pat_chars[p * NN + n];
        if (c == 255) continue;        // wildcard column
        has_any = true;
        if (c == 254) { dead = true; continue; }
        uint64_t lo = bb[c * WW + w];
        uint64_t hi = (w < WW - 1) ? bb[c * WW + w + 1] : 0ULL;
        uint64_t word = (p == 0) ? lo : ((lo >> p) | (hi << (64 - p)));
        m &= word;
    }
    if (dead) m = 0ULL;
    // pad region: s in [2036,2048) must be 0 when pattern_sums > 0
    if (w == WW - 1 && has_any) m &= ((1ULL << 52) - 1);

    masks[nl][w] = m;
    __syncthreads();

    // Phase B: write 8 rows x 2048 floats, coalesced float4
    size_t base = ((size_t)b * NN + (size_t)ng * 8) * SS;
#pragma unroll
    for (int r = 0; r < 8; ++r) {
        float4* rowp = (float4*)(out + base + (size_t)r * SS);
#pragma unroll
        for (int j = 0; j < 2; ++j) {
            int i4 = t + j * 256;              // float4 index within row [0,512)
            uint64_t mm = masks[r][i4 >> 4];
            int sh = (i4 & 15) * 4;
            float4 v;
            v.x = ((mm >> (sh + 0)) & 1ULL) ? 1.f : 0.f;
            v.y = ((mm >> (sh + 1)) & 1ULL) ? 1.f : 0.f;
            v.z = ((mm >> (sh + 2)) & 1ULL) ? 1.f : 0.f;
            v.w = ((mm >> (sh + 3)) & 1ULL) ? 1.f : 0.f;
            rowp[i4] = v;
        }
    }
}

// ---------------------------------------------------------------------------
extern "C" void kernel_launch(void* const* d_in, const int* in_sizes, int n_in,
                              void* d_out, int out_size, void* d_ws, size_t ws_size,
                              hipStream_t stream) {
    const float* input_   = (const float*)d_in[0];   // [32,30,2048,1]
    const float* patterns = (const float*)d_in[1];   // [30,13,1,512]
    float* out = (float*)d_out;                      // [32,512,2048,1]

    uint8_t*  pat_chars = (uint8_t*)d_ws;                          // 6656 B
    uint64_t* bits      = (uint64_t*)((char*)d_ws + 8192);         // 245760 B

    // K1: fused bits (960 blocks) + discretize (26 blocks)
    k_prep<<<NB_BITS + NB_DISC, 256, 0, stream>>>(input_, patterns, bits, pat_chars);
    // K2: one block per (b, group-of-8 n) -> 32*64 = 2048 blocks
    k_match<<<BB * (NN / 8), 256, 0, stream>>>(pat_chars, bits, out);
}

// Round 5
// 33.851 us; speedup vs baseline: 1.2699x; 1.0323x over previous
//
#include <hip/hip_runtime.h>
#include <stdint.h>

// Problem constants (from reference setup_inputs)
#define BB   32      // batch
#define SS   2048    // sequence length
#define NCH  30      // char alphabet
#define PP   13      // pattern length
#define NN   512     // number of patterns
#define WW   32      // SS / 64 bit-words per row

#define NB_BITS (BB * NCH)                 // 960 blocks: one per (b,c) row
#define NB_DISC ((PP * NN + 255) / 256)    // 26 blocks for discretize

// ---------------------------------------------------------------------------
// Kernel 1 (fused prep):
//  blocks [0, NB_BITS): build per-(b,c) occurrence bitmaps via __ballot.
//  blocks [NB_BITS, ...): discretize patterns [c=30][p=13][1][n=512].
//    Per column: argmax char; 255 = wildcard (col sum <= 0); 254 = dead
//    (tied max -> pattern_sums >= conv_max+1 -> never matches).
// ---------------------------------------------------------------------------
__global__ void k_prep(const float* __restrict__ input_,
                       const float* __restrict__ patterns,
                       uint64_t* __restrict__ bits,
                       uint8_t* __restrict__ pat_chars) {
    const int bid = blockIdx.x;
    const int t   = threadIdx.x;
    if (bid < NB_BITS) {
        const int wave = t >> 6;
        const int lane = t & 63;
        const float*   row  = input_ + (size_t)bid * SS;
        uint64_t*      brow = bits + (size_t)bid * WW;
#pragma unroll
        for (int i = 0; i < 8; ++i) {
            int w = wave * 8 + i;
            float v = row[w * 64 + lane];
            uint64_t m = __ballot(v > 0.5f);
            if (lane == 0) brow[w] = m;
        }
    } else {
        int col = (bid - NB_BITS) * 256 + t;   // p*NN + n
        if (col < PP * NN) {
            float mx = -1e30f;
            float sum = 0.f;
            int arg = 0;
            for (int c = 0; c < NCH; ++c) {
                float v = patterns[(size_t)c * (PP * NN) + col];
                sum += v;
                if (v > mx) { mx = v; arg = c; }
            }
            int cnt = 0;
            for (int c = 0; c < NCH; ++c) {
                float v = patterns[(size_t)c * (PP * NN) + col];
                cnt += (v == mx) ? 1 : 0;
            }
            uint8_t o;
            if (!(sum > 0.f))  o = 255;       // wildcard column
            else if (cnt > 1)  o = 254;       // dead pattern marker
            else               o = (uint8_t)arg;
            pat_chars[col] = o;
        }
    }
}

// ---------------------------------------------------------------------------
// Kernel 2: bit-parallel match + DECOUPLED output write.
// Block = 256 threads, one b and 8 consecutive n.
// Phase 0: unconditional zero-fill of the block's 64 KB output region —
//          a pure, dependency-free store stream (fill-kernel shaped),
//          issued before any mask computation so it overlaps phase A.
// Phase A: 64 match bits per (n_local, w) via 13 shifted ANDs of char
//          bitmaps.  Tail s >= 2036 cleared (conv pad) unless pattern has
//          zero constraints.  Masks -> LDS.
// Phase B: after __syncthreads (implies vmcnt(0) drain -> zeros committed),
//          sparse overwrite of 1.0f at set bits.  Each thread overwrites
//          only addresses it zeroed itself (same-thread ordering).  With
//          random one-hot data, matches are ~never -> branch uniform-false.
// ---------------------------------------------------------------------------
__global__ void k_match(const uint8_t* __restrict__ pat_chars,
                        const uint64_t* __restrict__ bits,
                        float* __restrict__ out) {
    __shared__ uint64_t masks[8][WW];
    const int b  = blockIdx.x >> 6;    // 64 n-groups of 8 per batch
    const int ng = blockIdx.x & 63;
    const int t  = threadIdx.x;
    const int nl = t >> 5;
    const int w  = t & (WW - 1);
    const int n  = ng * 8 + nl;
    const size_t base = ((size_t)b * NN + (size_t)ng * 8) * SS;

    // Phase 0: blast zeros (no dependencies)
    float4 z; z.x = z.y = z.z = z.w = 0.f;
#pragma unroll
    for (int r = 0; r < 8; ++r) {
        float4* rowp = (float4*)(out + base + (size_t)r * SS);
        rowp[t]       = z;
        rowp[t + 256] = z;
    }

    // Phase A: match bits
    const uint64_t* bb = bits + (size_t)b * NCH * WW;
    uint64_t m = ~0ULL;
    bool has_any = false;   // sums > 0 ?
    bool dead    = false;
#pragma unroll
    for (int p = 0; p < PP; ++p) {
        int c = pat_chars[p * NN + n];
        if (c == 255) continue;        // wildcard column
        has_any = true;
        if (c == 254) { dead = true; continue; }
        uint64_t lo = bb[c * WW + w];
        uint64_t hi = (w < WW - 1) ? bb[c * WW + w + 1] : 0ULL;
        uint64_t word = (p == 0) ? lo : ((lo >> p) | (hi << (64 - p)));
        m &= word;
    }
    if (dead) m = 0ULL;
    // pad region: s in [2036,2048) must be 0 when pattern_sums > 0
    if (w == WW - 1 && has_any) m &= ((1ULL << 52) - 1);

    masks[nl][w] = m;
    __syncthreads();   // barrier + implied vmcnt(0): zero stores committed

    // Phase B: sparse 1.0f overwrites (same thread owns same addresses)
#pragma unroll
    for (int r = 0; r < 8; ++r) {
#pragma unroll
        for (int j = 0; j < 2; ++j) {
            int i4 = t + j * 256;              // float4 index within row
            uint32_t nib =
                (uint32_t)((masks[r][i4 >> 4] >> ((i4 & 15) * 4)) & 0xFULL);
            if (nib) {
                float* p = out + base + (size_t)r * SS + (size_t)i4 * 4;
                if (nib & 1u) p[0] = 1.f;
                if (nib & 2u) p[1] = 1.f;
                if (nib & 4u) p[2] = 1.f;
                if (nib & 8u) p[3] = 1.f;
            }
        }
    }
}

// ---------------------------------------------------------------------------
extern "C" void kernel_launch(void* const* d_in, const int* in_sizes, int n_in,
                              void* d_out, int out_size, void* d_ws, size_t ws_size,
                              hipStream_t stream) {
    const float* input_   = (const float*)d_in[0];   // [32,30,2048,1]
    const float* patterns = (const float*)d_in[1];   // [30,13,1,512]
    float* out = (float*)d_out;                      // [32,512,2048,1]

    uint8_t*  pat_chars = (uint8_t*)d_ws;                          // 6656 B
    uint64_t* bits      = (uint64_t*)((char*)d_ws + 8192);         // 245760 B

    // K1: fused bits (960 blocks) + discretize (26 blocks)
    k_prep<<<NB_BITS + NB_DISC, 256, 0, stream>>>(input_, patterns, bits, pat_chars);
    // K2: one block per (b, group-of-8 n) -> 32*64 = 2048 blocks
    k_match<<<BB * (NN / 8), 256, 0, stream>>>(pat_chars, bits, out);
}

// Round 6
// 21.307 us; speedup vs baseline: 2.0176x; 1.5888x over previous
//
#include <hip/hip_runtime.h>
#include <stdint.h>

// Problem constants (from reference setup_inputs)
#define BB   32      // batch
#define SS   2048    // sequence length
#define NCH  30      // char alphabet
#define PP   13      // pattern length
#define NN   512     // number of patterns
#define WW   32      // SS / 64 bit-words per row

#define NB_BITS (BB * NCH)                 // 960 prep-blocks: one per (b,c) row
#define NB_DISC ((PP * NN + 255) / 256)    // 26 blocks for discretize
#define NBLK    (BB * NN / 8)              // 2048 blocks total (fill + match grids)

// ---------------------------------------------------------------------------
// Kernel 1: zero-fill of the ENTIRE output (the mandatory 128 MB write,
// dependency-free, fill-kernel shaped) + prep work hidden under it.
//  - every block: zero-fill its 64 KB chunk (4 float4 stores/thread).
//  - blocks [0, NB_BITS): also build per-(b,c) occurrence bitmaps (__ballot).
//  - blocks [NB_BITS, NB_BITS+NB_DISC): also discretize patterns
//    [c=30][p=13][1][n=512]: per column argmax char; 255 = wildcard
//    (col sum <= 0); 254 = dead (tied max -> never matches).
// Critical path = fill (~20 us at demonstrated ~6.7 TB/s); prep adds ~2 us
// to 986 of 2048 blocks only.
// ---------------------------------------------------------------------------
__global__ void k_fill_prep(const float* __restrict__ input_,
                            const float* __restrict__ patterns,
                            float* __restrict__ out,
                            uint64_t* __restrict__ bits,
                            uint8_t* __restrict__ pat_chars) {
    const int bid = blockIdx.x;
    const int t   = threadIdx.x;

    // prep (first, so its loads issue before the store blast)
    if (bid < NB_BITS) {
        const int wave = t >> 6;
        const int lane = t & 63;
        const float*   row  = input_ + (size_t)bid * SS;
        uint64_t*      brow = bits + (size_t)bid * WW;
#pragma unroll
        for (int i = 0; i < 8; ++i) {
            int w = wave * 8 + i;
            float v = row[w * 64 + lane];
            uint64_t m = __ballot(v > 0.5f);
            if (lane == 0) brow[w] = m;
        }
    } else if (bid < NB_BITS + NB_DISC) {
        int col = (bid - NB_BITS) * 256 + t;   // p*NN + n
        if (col < PP * NN) {
            float mx = -1e30f;
            float sum = 0.f;
            int arg = 0;
            for (int c = 0; c < NCH; ++c) {
                float v = patterns[(size_t)c * (PP * NN) + col];
                sum += v;
                if (v > mx) { mx = v; arg = c; }
            }
            int cnt = 0;
            for (int c = 0; c < NCH; ++c) {
                float v = patterns[(size_t)c * (PP * NN) + col];
                cnt += (v == mx) ? 1 : 0;
            }
            uint8_t o;
            if (!(sum > 0.f))  o = 255;       // wildcard column
            else if (cnt > 1)  o = 254;       // dead pattern marker
            else               o = (uint8_t)arg;
            pat_chars[col] = o;
        }
    }

    // zero-fill: 64 KB contiguous chunk per block, 4 x float4 per thread
    float4 z; z.x = z.y = z.z = z.w = 0.f;
    float4* chunk = (float4*)(out + (size_t)bid * (SS * 8));  // 16384 floats
#pragma unroll
    for (int j = 0; j < 4; ++j)
        chunk[t + j * 256] = z;
}

// ---------------------------------------------------------------------------
// Kernel 2: bit-parallel match, sparse-write only.
// Thread (b, n, w) computes 64 match bits via 13 shifted ANDs of the char
// bitmaps (L2-hot 245 KB table).  Tail s >= 2036 cleared (conv pad) unless
// the pattern has zero constraints.  Zeros were committed by k1 (kernel
// boundary = full drain), so only the (essentially never occurring) 1.0
// positions are written here, via set-bit iteration.
// ---------------------------------------------------------------------------
__global__ void k_match(const uint8_t* __restrict__ pat_chars,
                        const uint64_t* __restrict__ bits,
                        float* __restrict__ out) {
    const int b  = blockIdx.x >> 6;    // 64 n-groups of 8 per batch
    const int ng = blockIdx.x & 63;
    const int t  = threadIdx.x;
    const int nl = t >> 5;
    const int w  = t & (WW - 1);
    const int n  = ng * 8 + nl;

    const uint64_t* bb = bits + (size_t)b * NCH * WW;

    uint64_t m = ~0ULL;
    bool has_any = false;   // sums > 0 ?
    bool dead    = false;
#pragma unroll
    for (int p = 0; p < PP; ++p) {
        int c = pat_chars[p * NN + n];
        if (c == 255) continue;        // wildcard column
        has_any = true;
        if (c == 254) { dead = true; continue; }
        uint64_t lo = bb[c * WW + w];
        uint64_t hi = (w < WW - 1) ? bb[c * WW + w + 1] : 0ULL;
        uint64_t word = (p == 0) ? lo : ((lo >> p) | (hi << (64 - p)));
        m &= word;
    }
    if (dead) m = 0ULL;
    // pad region: s in [2036,2048) must be 0 when pattern_sums > 0
    if (w == WW - 1 && has_any) m &= ((1ULL << 52) - 1);

    if (m) {
        float* rowp = out + ((size_t)b * NN + n) * SS + w * 64;
        do {
            int bpos = __builtin_ctzll(m);
            rowp[bpos] = 1.f;
            m &= m - 1;
        } while (m);
    }
}

// ---------------------------------------------------------------------------
extern "C" void kernel_launch(void* const* d_in, const int* in_sizes, int n_in,
                              void* d_out, int out_size, void* d_ws, size_t ws_size,
                              hipStream_t stream) {
    const float* input_   = (const float*)d_in[0];   // [32,30,2048,1]
    const float* patterns = (const float*)d_in[1];   // [30,13,1,512]
    float* out = (float*)d_out;                      // [32,512,2048,1]

    uint8_t*  pat_chars = (uint8_t*)d_ws;                          // 6656 B
    uint64_t* bits      = (uint64_t*)((char*)d_ws + 8192);         // 245760 B

    // K1: 2048 blocks — full output zero-fill + prep hidden underneath
    k_fill_prep<<<NBLK, 256, 0, stream>>>(input_, patterns, out, bits, pat_chars);
    // K2: 2048 blocks — match, sparse writes only
    k_match<<<NBLK, 256, 0, stream>>>(pat_chars, bits, out);
}